// Round 11
// baseline (241.483 us; speedup 1.0000x reference)
//
#include <hip/hip_runtime.h>
#include <hip/hip_fp16.h>

// Tree NN: reps = emb[tokens] (4096 x 128 x 128); 7x: reps = tanh(concat(pairs) @ W_tree^T + b);
// out = root @ W_cls^T + b_cls.
//
// R11: direct-global L0. R10 lessons: (1) allocator VGPR cap = 512/(2*launch_bounds_min)
// (R2:(256,2)->128, R3:(256,3)->80, R10:(256,4)->64 -> L0-split spilled 7.3MB); (2) per-CU
// LDS bandwidth (~40-55k cyc/CU: every wave redundantly reads each level's FULL A-tile) +
// 31k conflict cyc/CU is the binding shared pipe -- more blocks/CU alone doesn't scale.
// Change: L0 consumes the embedding DIRECTLY from global (per-lane 2x dwordx4 per kstep,
// L1/L2-hot across the block's 4 waves; K-split chains map to leaf0/leaf1 = tok.x/tok.y).
// Gather stage, leaf LDS storage, L0 LDS reads, and the conflicted gather ds_writes all
// vanish. bufA 48 rows -> LDS 29.7 KB; barriers/pair 14 -> 12; launch_bounds(256,2)
// -> cap 128 >= demand ~120 -> no spill, 4 waves/EU -> 4 blocks/CU (~50% occupancy).
// Tripwire: WRITE_SIZE in tens of MB = spill -> revert.
//
// Wave w owns output n-tiles {2w,2w+1} at every level (Wf[2][8] = 64 VGPR of W-fragments).
// Row rotation in one 48-row buffer: L0(global)->rows 0-31; L1 0-31->32-47; L2 32-47->0-7;
// L3 0-15(8-15 stale,masked)->bufC stash; batched L4 bufC->rows 0-3; L5 0-3->4-5; L6+cls.
// Stale rows are always finite tanh/leaf values -- never uninitialized before first use.
// fp16 MFMA 16x16x32 (K-split 2 independent 4-chains), fp32 accumulate/tanh/classifier.

typedef _Float16 half8 __attribute__((ext_vector_type(8)));
typedef float floatx4 __attribute__((ext_vector_type(4)));

#define STRIDE 264   // 256 + 8 fp16 pad: A-row ds_read_b128 conflict-free
#define NPAIR 2048

__device__ __forceinline__ float fast_tanh(float x) {
  // No clamp needed: e=inf -> 1; e=0 -> -1. Inputs never NaN.
  float e = __expf(2.f * x);
  return 1.f - 2.f * __builtin_amdgcn_rcpf(e + 1.f);
}

__device__ __forceinline__ unsigned pkrtz(float a, float b) {
  auto h = __builtin_amdgcn_cvt_pkrtz(a, b);   // __fp16 ext_vector(2)
  return __builtin_bit_cast(unsigned, h);
}

__device__ __forceinline__ half8 pack8(float4 a, float4 b) {
  uint4 u;
  u.x = pkrtz(a.x, a.y); u.y = pkrtz(a.z, a.w);
  u.z = pkrtz(b.x, b.y); u.w = pkrtz(b.z, b.w);
  return __builtin_bit_cast(half8, u);
}

// K=256 LDS MFMA for one 16-row m-tile, 2 n-tiles, K-split into 2 independent 4-chains.
// A-frag: A[m=lane&15][k=quad*8+j]; B-frag: B[k=quad*8+j][n=lane&15];
// D: col=lane&15, row=quad*4+reg (verified layouts, learn_hip m89/m91).
__device__ __forceinline__ void mfma_k256(const _Float16* arow, const half8 (&Wf)[2][8],
                                          floatx4 (&accO)[2]) {
  floatx4 aA[2], aB[2];
  aA[0] = (floatx4){0.f, 0.f, 0.f, 0.f}; aA[1] = (floatx4){0.f, 0.f, 0.f, 0.f};
  aB[0] = (floatx4){0.f, 0.f, 0.f, 0.f}; aB[1] = (floatx4){0.f, 0.f, 0.f, 0.f};
#pragma unroll
  for (int ks = 0; ks < 4; ++ks) {
    half8 x0 = *(const half8*)(arow + ks * 32);
    half8 x1 = *(const half8*)(arow + (ks + 4) * 32);
    aA[0] = __builtin_amdgcn_mfma_f32_16x16x32_f16(x0, Wf[0][ks],     aA[0], 0, 0, 0);
    aB[0] = __builtin_amdgcn_mfma_f32_16x16x32_f16(x1, Wf[0][ks + 4], aB[0], 0, 0, 0);
    aA[1] = __builtin_amdgcn_mfma_f32_16x16x32_f16(x0, Wf[1][ks],     aA[1], 0, 0, 0);
    aB[1] = __builtin_amdgcn_mfma_f32_16x16x32_f16(x1, Wf[1][ks + 4], aB[1], 0, 0, 0);
  }
  accO[0] = aA[0] + aB[0];
  accO[1] = aA[1] + aB[1];
}

// LDS-fed level: read MT m-tiles at INROW, store tanh'd nodes (node<MOUT) at
// OUTROW+(node>>1), half (node&1). CLAMP8: clamp read row to <8 (bufC is 8 rows).
template<int MT, int MOUT, int INROW, int OUTROW, bool CLAMP8>
__device__ __forceinline__ void level_ip(
    const _Float16* inb, _Float16* outb,
    const half8 (&Wf)[2][8], const float (&bias)[2],
    int nbase, int l15, int quad)
{
  floatx4 acc[MT][2];
  if (MT == 1) {
    const int rr = CLAMP8 ? (l15 < 8 ? l15 : 7) : l15;
    mfma_k256(inb + (INROW + rr) * STRIDE + quad * 8, Wf, acc[0]);
  } else {
#pragma unroll
    for (int m = 0; m < MT; ++m) {
      acc[m][0] = (floatx4){0.f, 0.f, 0.f, 0.f};
      acc[m][1] = (floatx4){0.f, 0.f, 0.f, 0.f};
    }
#pragma unroll
    for (int m = 0; m < MT; ++m) {
      const _Float16* arow = inb + (INROW + m * 16 + l15) * STRIDE + quad * 8;
#pragma unroll
      for (int ks = 0; ks < 8; ++ks) {
        half8 a = *(const half8*)(arow + ks * 32);
        acc[m][0] = __builtin_amdgcn_mfma_f32_16x16x32_f16(a, Wf[0][ks], acc[m][0], 0, 0, 0);
        acc[m][1] = __builtin_amdgcn_mfma_f32_16x16x32_f16(a, Wf[1][ks], acc[m][1], 0, 0, 0);
      }
    }
  }

  const int mrow = quad * 4;
#pragma unroll
  for (int m = 0; m < MT; ++m)
#pragma unroll
    for (int i = 0; i < 2; ++i) {
      const int col = (nbase + i) * 16 + l15;
#pragma unroll
      for (int r = 0; r < 4; ++r) {
        const int node = m * 16 + mrow + r;
        if (node < MOUT) {
          float v = fast_tanh(acc[m][i][r] + bias[i]);
          outb[(OUTROW + (node >> 1)) * STRIDE + (node & 1) * 128 + col] = (_Float16)v;
        }
      }
    }
}

// L0 fed directly from global: m-tile row (16m+l15) is the leaf-pair (tok.x, tok.y);
// K-split chain A (ks 0-3) = leaf0 features, chain B (ks 4-7) = leaf1 features.
__device__ __forceinline__ void l0_direct(
    const int* __restrict__ tokS, const float* __restrict__ emb, _Float16* outb,
    const half8 (&Wf)[2][8], const float (&bias)[2],
    int nbase, int l15, int quad)
{
#pragma unroll 1
  for (int m = 0; m < 4; ++m) {
    const int2 tk = *(const int2*)(tokS + 32 * m + 2 * l15);
    const float* b0 = emb + (size_t)tk.x * 128 + quad * 8;
    const float* b1 = emb + (size_t)tk.y * 128 + quad * 8;
    floatx4 aA[2], aB[2];
    aA[0] = (floatx4){0.f, 0.f, 0.f, 0.f}; aA[1] = (floatx4){0.f, 0.f, 0.f, 0.f};
    aB[0] = (floatx4){0.f, 0.f, 0.f, 0.f}; aB[1] = (floatx4){0.f, 0.f, 0.f, 0.f};
#pragma unroll
    for (int ks = 0; ks < 4; ++ks) {
      float4 x0 = *(const float4*)(b0 + ks * 32);
      float4 x1 = *(const float4*)(b0 + ks * 32 + 4);
      float4 y0 = *(const float4*)(b1 + ks * 32);
      float4 y1 = *(const float4*)(b1 + ks * 32 + 4);
      half8 hx = pack8(x0, x1);
      half8 hy = pack8(y0, y1);
      aA[0] = __builtin_amdgcn_mfma_f32_16x16x32_f16(hx, Wf[0][ks],     aA[0], 0, 0, 0);
      aB[0] = __builtin_amdgcn_mfma_f32_16x16x32_f16(hy, Wf[0][ks + 4], aB[0], 0, 0, 0);
      aA[1] = __builtin_amdgcn_mfma_f32_16x16x32_f16(hx, Wf[1][ks],     aA[1], 0, 0, 0);
      aB[1] = __builtin_amdgcn_mfma_f32_16x16x32_f16(hy, Wf[1][ks + 4], aB[1], 0, 0, 0);
    }
    floatx4 acc[2] = {aA[0] + aB[0], aA[1] + aB[1]};

    const int mrow = quad * 4;
#pragma unroll
    for (int i = 0; i < 2; ++i) {
      const int col = (nbase + i) * 16 + l15;
#pragma unroll
      for (int r = 0; r < 4; ++r) {
        const int node = m * 16 + mrow + r;           // < 64 always valid
        float v = fast_tanh(acc[i][r] + bias[i]);
        outb[(node >> 1) * STRIDE + (node & 1) * 128 + col] = (_Float16)v;
      }
    }
  }
}

__global__ __launch_bounds__(256, 2)   // allocator cap = 512/(2*2) = 128 VGPR: no spill
void tree_kernel(const int* __restrict__ tokens,
                 const float* __restrict__ embedding,
                 const float* __restrict__ W_tree,
                 const float* __restrict__ b_tree,
                 const float* __restrict__ W_cls,
                 const float* __restrict__ b_cls,
                 float* __restrict__ out)
{
  __shared__ __align__(16) _Float16 bufA[48 * STRIDE];   // all levels, row-rotated (25.3 KB)
  __shared__ __align__(16) _Float16 bufC[8 * STRIDE];    // pair stash: L3 outs (4.2 KB)
  __shared__ float wavepart[4][2][3];                    // classifier partials (96 B)

  const int tid  = threadIdx.x;
  const int wid  = tid >> 6;
  const int lane = tid & 63;
  const int l15  = lane & 15;
  const int quad = lane >> 4;
  const int nbase = wid * 2;               // this wave's n-tile base (features [32*wid,32*wid+32))

  // ---- stage this wave's 2 n-tiles of W_tree as B-fragments (64 VGPR) ----
  // B[k][n] = W_tree[e=n][h=k]  (einsum 'bnh,eh->bne' => out = comb @ W^T)
  half8 Wf[2][8];
#pragma unroll
  for (int i = 0; i < 2; ++i) {
    const int e = (nbase + i) * 16 + l15;
#pragma unroll
    for (int ks = 0; ks < 8; ++ks) {
      const int k = ks * 32 + quad * 8;
      const float4* p = (const float4*)(W_tree + e * 256 + k);
      float4 lo = p[0], hi = p[1];
      half8 f;
      f[0] = (_Float16)lo.x; f[1] = (_Float16)lo.y; f[2] = (_Float16)lo.z; f[3] = (_Float16)lo.w;
      f[4] = (_Float16)hi.x; f[5] = (_Float16)hi.y; f[6] = (_Float16)hi.z; f[7] = (_Float16)hi.w;
      Wf[i][ks] = f;
    }
  }
  float bias[2];
#pragma unroll
  for (int i = 0; i < 2; ++i) bias[i] = b_tree[(nbase + i) * 16 + l15];

  // classifier weights for this lane's 2 columns: loop-invariant (6 VGPR)
  float wc[2][3];
#pragma unroll
  for (int i = 0; i < 2; ++i) {
    const int col = (nbase + i) * 16 + l15;
#pragma unroll
    for (int o = 0; o < 3; ++o) wc[i][o] = W_cls[o * 128 + col];
  }

#pragma unroll 1
  for (int p = blockIdx.x; p < NPAIR; p += gridDim.x) {

    // ---- phase 1 per sample: L0 direct-global + L1,L2 in-place + L3 -> bufC stash ----
#pragma unroll 1
    for (int j = 0; j < 2; ++j) {
      const int s = 2 * p + j;
      // L0: global -> rows 0-31
      l0_direct(tokens + s * 128, embedding, bufA, Wf, bias, nbase, l15, quad);
      __syncthreads();
      // L1: rows 0-31 -> 32-47
      level_ip<2, 32, 0, 32, false>(bufA, bufA, Wf, bias, nbase, l15, quad);
      __syncthreads();
      // L2: rows 32-47 -> 0-7
      level_ip<1, 16, 32, 0, false>(bufA, bufA, Wf, bias, nbase, l15, quad);
      __syncthreads();
      // L3: rows 0-15 (8-15 stale L0-out, finite, masked by MOUT=8) -> bufC [4j,4j+4)
      level_ip<1,  8, 0,  0, false>(bufA, bufC + j * 4 * STRIDE, Wf, bias, nbase, l15, quad);
      __syncthreads();
    }

    // ---- batched L4: bufC rows 0-7 (s0: 0-3, s1: 4-7) -> bufA rows 0-3 ----
    level_ip<1, 8, 0, 0, true>(bufC, bufA, Wf, bias, nbase, l15, quad);
    __syncthreads();
    // ---- batched L5: bufA rows 0-3 -> rows 4-5 (s0: 4, s1: 5) ----
    level_ip<1, 4, 0, 4, false>(bufA, bufA, Wf, bias, nbase, l15, quad);
    __syncthreads();

    // ---- batched L6 + classifier partials from registers ----
    {
      floatx4 acc[2];
      mfma_k256(bufA + (4 + l15) * STRIDE + quad * 8, Wf, acc);  // m-rows 0,1 = roots s0,s1
      float part[2][3] = {{0.f, 0.f, 0.f}, {0.f, 0.f, 0.f}};
      if (quad == 0) {
#pragma unroll
        for (int i = 0; i < 2; ++i) {
#pragma unroll
          for (int rr = 0; rr < 2; ++rr) {           // rr = sample
            float v = fast_tanh(acc[i][rr] + bias[i]);
#pragma unroll
            for (int o = 0; o < 3; ++o) part[rr][o] = fmaf(v, wc[i][o], part[rr][o]);
          }
        }
      }
#pragma unroll
      for (int rr = 0; rr < 2; ++rr) {
#pragma unroll
        for (int o = 0; o < 3; ++o) {
          float v = part[rr][o];                     // nonzero only in quad-0 lanes
          v += __shfl_down(v, 8);
          v += __shfl_down(v, 4);
          v += __shfl_down(v, 2);
          v += __shfl_down(v, 1);
          if (lane == 0) wavepart[wid][rr][o] = v;
        }
      }
    }
    __syncthreads();
    if (tid < 6) {
      const int rr = tid / 3, o = tid - 3 * rr;
      float v = wavepart[0][rr][o] + wavepart[1][rr][o]
              + wavepart[2][rr][o] + wavepart[3][rr][o];
      out[(2 * p + rr) * 3 + o] = v + b_cls[o];
    }
    // next pair's L0 overwrites bufA rows 0-31: all L6 bufA reads completed before the
    // wavepart barrier; wavepart next written 10+ barriers later -> safe.
  }
}

extern "C" void kernel_launch(void* const* d_in, const int* in_sizes, int n_in,
                              void* d_out, int out_size, void* d_ws, size_t ws_size,
                              hipStream_t stream) {
  const int*   tokens    = (const int*)d_in[0];
  const float* embedding = (const float*)d_in[1];
  const float* W_tree    = (const float*)d_in[2];
  const float* b_tree    = (const float*)d_in[3];
  const float* W_cls     = (const float*)d_in[4];
  const float* b_cls     = (const float*)d_in[5];
  float* out = (float*)d_out;

  dim3 grid(1024), block(256);   // 4 blocks/CU x 256 CUs; 2 pairs per block
  tree_kernel<<<grid, block, 0, stream>>>(tokens, embedding, W_tree, b_tree, W_cls, b_cls, out);
}

// Round 12
// 183.705 us; speedup vs baseline: 1.3145x; 1.3145x over previous
//
#include <hip/hip_runtime.h>
#include <hip/hip_fp16.h>

// Tree NN: reps = emb[tokens] (4096 x 128 x 128); 7x: reps = tanh(concat(pairs) @ W_tree^T + b);
// out = root @ W_cls^T + b_cls.
//
// R12 = R9 (best: 85us dispatch) + three counter-driven fixes:
//  1. Conflict-free gather writes: thread t -> row t&63, seg t>>6; 8 consecutive lanes hit
//     8 consecutive rows -> bank-quad (row+j)%8 distinct. (R11 showed 5.4M of R9's 8.26M
//     conflict cycles were the old (leaf>>1)*33 gather-write pattern.)
//  2. Tail retargeted to bufB (dead after L3(s1)) -> bufA free during L5/L6; next pair's
//     s0-gather loads+packs+writes happen INSIDE the L5/L6 sections (8+8 uint4, transient
//     regs only, never held across a barrier -- the R4-R7 spill trap). Writes land before
//     the existing wavepart barrier: no new barriers, one gather latency/pair hidden.
//  3. launch_bounds(256,2): allocator cap = 512/(2*min) = 128 (law measured R2/R3/R10);
//     demand ~120 fits. LDS 53,248 unchanged -> 3 blocks/CU (159.7 <= 160 KB).
//  Tripwire: WRITE_SIZE in MBs = spill -> revert prefetch.
//
// Wave w owns output n-tiles {2w,2w+1} at every level (Wf[2][8] = 64 VGPR of W-fragments).
// Activations in LDS, pair-contiguous so concat(left,right) is free. Per-sample phase-1
// gather,L0..L4 (stash L4-out in bufC); batched tail L5,L6+classifier per pair.
// fp16 MFMA 16x16x32 (K-split 2 independent 4-chains), fp32 accumulate/tanh/classifier.

typedef _Float16 half8 __attribute__((ext_vector_type(8)));
typedef float floatx4 __attribute__((ext_vector_type(4)));

#define STRIDE 264   // 256 + 8 fp16 pad: A-row ds_read_b128 conflict-free
#define UROW   33    // uint4 per row
#define NPAIR  2048

__device__ __forceinline__ float fast_tanh(float x) {
  // No clamp needed: e=inf -> 1; e=0 -> -1. Inputs never NaN.
  float e = __expf(2.f * x);
  return 1.f - 2.f * __builtin_amdgcn_rcpf(e + 1.f);
}

__device__ __forceinline__ unsigned pkrtz(float a, float b) {
  auto h = __builtin_amdgcn_cvt_pkrtz(a, b);   // __fp16 ext_vector(2)
  return __builtin_bit_cast(unsigned, h);
}

// Gather segment: thread (row, seg) covers leaf 2*row+(seg>>1), feature half (seg&1).
// Writes uint4 j in [J0,J1) at row*33 + seg*8 + j -> conflict-free phases (row+j distinct).
template<int J0, int J1>
__device__ __forceinline__ void gather_chunk(int tok, const float* __restrict__ emb,
                                             _Float16* buf, int row, int seg) {
  const float4* src = (const float4*)emb + (size_t)tok * 32 + (seg & 1) * 16;
  uint4* dst = (uint4*)buf + row * UROW + seg * 8;
#pragma unroll
  for (int j = J0; j < J1; ++j) {
    float4 x = src[2 * j], y = src[2 * j + 1];
    uint4 w;
    w.x = pkrtz(x.x, x.y); w.y = pkrtz(x.z, x.w);
    w.z = pkrtz(y.x, y.y); w.w = pkrtz(y.z, y.w);
    dst[j] = w;
  }
}

// K=256 MFMA for one 16-row m-tile, 2 n-tiles, K-split into 2 independent 4-chains.
// A-frag: A[m=lane&15][k=quad*8+j]; B-frag: B[k=quad*8+j][n=lane&15];
// D: col=lane&15, row=quad*4+reg (verified layouts, learn_hip m89/m91).
__device__ __forceinline__ void mfma_k256(const _Float16* arow, const half8 (&Wf)[2][8],
                                          floatx4 (&accO)[2]) {
  floatx4 aA[2], aB[2];
  aA[0] = (floatx4){0.f, 0.f, 0.f, 0.f}; aA[1] = (floatx4){0.f, 0.f, 0.f, 0.f};
  aB[0] = (floatx4){0.f, 0.f, 0.f, 0.f}; aB[1] = (floatx4){0.f, 0.f, 0.f, 0.f};
#pragma unroll
  for (int ks = 0; ks < 4; ++ks) {
    half8 x0 = *(const half8*)(arow + ks * 32);
    half8 x1 = *(const half8*)(arow + (ks + 4) * 32);
    aA[0] = __builtin_amdgcn_mfma_f32_16x16x32_f16(x0, Wf[0][ks],     aA[0], 0, 0, 0);
    aB[0] = __builtin_amdgcn_mfma_f32_16x16x32_f16(x1, Wf[0][ks + 4], aB[0], 0, 0, 0);
    aA[1] = __builtin_amdgcn_mfma_f32_16x16x32_f16(x0, Wf[1][ks],     aA[1], 0, 0, 0);
    aB[1] = __builtin_amdgcn_mfma_f32_16x16x32_f16(x1, Wf[1][ks + 4], aB[1], 0, 0, 0);
  }
  accO[0] = aA[0] + aB[0];
  accO[1] = aA[1] + aB[1];
}

// One wave: its 2 n-tiles for MT m-tiles; pair-contiguous store, MOUT row mask.
// Stale rows above MOUT always hold finite tanh/leaf values; masked at store.
template<int MT, int MOUT>
__device__ __forceinline__ void level_std(
    const _Float16* inb, _Float16* outb,
    const half8 (&Wf)[2][8], const float (&bias)[2],
    int nbase, int l15, int quad)
{
  floatx4 acc[MT][2];
  if (MT == 1) {
    floatx4 a2[2];
    mfma_k256(inb + l15 * STRIDE + quad * 8, Wf, a2);
    acc[0][0] = a2[0]; acc[0][1] = a2[1];
  } else {
#pragma unroll
    for (int m = 0; m < MT; ++m) {
      acc[m][0] = (floatx4){0.f, 0.f, 0.f, 0.f};
      acc[m][1] = (floatx4){0.f, 0.f, 0.f, 0.f};
    }
#pragma unroll
    for (int m = 0; m < MT; ++m) {
      const _Float16* arow = inb + (m * 16 + l15) * STRIDE + quad * 8;
#pragma unroll
      for (int ks = 0; ks < 8; ++ks) {
        half8 a = *(const half8*)(arow + ks * 32);
        acc[m][0] = __builtin_amdgcn_mfma_f32_16x16x32_f16(a, Wf[0][ks], acc[m][0], 0, 0, 0);
        acc[m][1] = __builtin_amdgcn_mfma_f32_16x16x32_f16(a, Wf[1][ks], acc[m][1], 0, 0, 0);
      }
    }
  }

  const int mrow = quad * 4;
#pragma unroll
  for (int m = 0; m < MT; ++m)
#pragma unroll
    for (int i = 0; i < 2; ++i) {
      const int col = (nbase + i) * 16 + l15;
#pragma unroll
      for (int r = 0; r < 4; ++r) {
        const int node = m * 16 + mrow + r;
        if (node < MOUT) {
          float v = fast_tanh(acc[m][i][r] + bias[i]);
          outb[(node >> 1) * STRIDE + (node & 1) * 128 + col] = (_Float16)v;
        }
      }
    }
}

__global__ __launch_bounds__(256, 2)   // cap = 512/(2*2) = 128 VGPR (allocator law, R2/R3/R10)
void tree_kernel(const int* __restrict__ tokens,
                 const float* __restrict__ embedding,
                 const float* __restrict__ W_tree,
                 const float* __restrict__ b_tree,
                 const float* __restrict__ W_cls,
                 const float* __restrict__ b_cls,
                 float* __restrict__ out)
{
  __shared__ __align__(16) _Float16 bufA[64 * STRIDE];   // leaves / even outputs (33.8 KB)
  __shared__ __align__(16) _Float16 bufB[32 * STRIDE];   // odd outputs + tail (16.9 KB)
  __shared__ __align__(16) _Float16 bufC[4 * STRIDE];    // pair stash: L4 outs (2.1 KB)
  __shared__ float wavepart[4][2][3];                    // classifier partials (96 B)

  const int tid  = threadIdx.x;
  const int wid  = tid >> 6;
  const int lane = tid & 63;
  const int l15  = lane & 15;
  const int quad = lane >> 4;
  const int nbase = wid * 2;               // this wave's n-tile base (features [32*wid,32*wid+32))
  const int row  = tid & 63;               // gather: destination row
  const int seg  = tid >> 6;               // gather: leaf-half / feature-half segment

  // ---- stage this wave's 2 n-tiles of W_tree as B-fragments (64 VGPR) ----
  // B[k][n] = W_tree[e=n][h=k]  (einsum 'bnh,eh->bne' => out = comb @ W^T)
  half8 Wf[2][8];
#pragma unroll
  for (int i = 0; i < 2; ++i) {
    const int e = (nbase + i) * 16 + l15;
#pragma unroll
    for (int ks = 0; ks < 8; ++ks) {
      const int k = ks * 32 + quad * 8;
      const float4* p = (const float4*)(W_tree + e * 256 + k);
      float4 lo = p[0], hi = p[1];
      half8 f;
      f[0] = (_Float16)lo.x; f[1] = (_Float16)lo.y; f[2] = (_Float16)lo.z; f[3] = (_Float16)lo.w;
      f[4] = (_Float16)hi.x; f[5] = (_Float16)hi.y; f[6] = (_Float16)hi.z; f[7] = (_Float16)hi.w;
      Wf[i][ks] = f;
    }
  }
  float bias[2];
#pragma unroll
  for (int i = 0; i < 2; ++i) bias[i] = b_tree[(nbase + i) * 16 + l15];

  // classifier weights for this lane's 2 columns: loop-invariant (6 VGPR)
  float wc[2][3];
#pragma unroll
  for (int i = 0; i < 2; ++i) {
    const int col = (nbase + i) * 16 + l15;
#pragma unroll
    for (int o = 0; o < 3; ++o) wc[i][o] = W_cls[o * 128 + col];
  }

  // ---- prologue: gather first pair's s0 into bufA ----
  {
    const int tok = tokens[(2 * blockIdx.x) * 128 + 2 * row + (seg >> 1)];
    gather_chunk<0, 8>(tok, embedding, bufA, row, seg);
  }
  __syncthreads();

#pragma unroll 1
  for (int p = blockIdx.x; p < NPAIR; p += gridDim.x) {
    int pn = p + gridDim.x;
    if (pn >= NPAIR) pn = p;               // last iteration: harmless self-reload
    int tokn;                              // prefetched token for next pair's s0 (1 VGPR)

    // ---- s0 phase-1 (leaves already in bufA from prologue / previous tail) ----
    level_std<4, 64>(bufA, bufB, Wf, bias, nbase, l15, quad);   // L0
    __syncthreads();
    level_std<2, 32>(bufB, bufA, Wf, bias, nbase, l15, quad);   // L1
    __syncthreads();
    level_std<1, 16>(bufA, bufB, Wf, bias, nbase, l15, quad);   // L2
    __syncthreads();
    level_std<1,  8>(bufB, bufA, Wf, bias, nbase, l15, quad);   // L3
    __syncthreads();
    level_std<1,  4>(bufA, bufC,            Wf, bias, nbase, l15, quad);  // L4 -> bufC rows 0-1
    __syncthreads();

    // ---- s1 gather (conflict-free writes) + prefetch next-s0 token ----
    {
      const int tok = tokens[(2 * p + 1) * 128 + 2 * row + (seg >> 1)];
      gather_chunk<0, 8>(tok, embedding, bufA, row, seg);
      tokn = tokens[(2 * pn) * 128 + 2 * row + (seg >> 1)];
    }
    __syncthreads();

    // ---- s1 phase-1 ----
    level_std<4, 64>(bufA, bufB, Wf, bias, nbase, l15, quad);   // L0
    __syncthreads();
    level_std<2, 32>(bufB, bufA, Wf, bias, nbase, l15, quad);   // L1
    __syncthreads();
    level_std<1, 16>(bufA, bufB, Wf, bias, nbase, l15, quad);   // L2
    __syncthreads();
    level_std<1,  8>(bufB, bufA, Wf, bias, nbase, l15, quad);   // L3
    __syncthreads();
    level_std<1,  4>(bufA, bufC + 2 * STRIDE, Wf, bias, nbase, l15, quad); // L4 -> bufC rows 2-3
    __syncthreads();

    // ---- batched L5: bufC rows 0-3 -> bufB rows 0-1; + prefetch chunk 0 into free bufA ----
    {
      gather_chunk<0, 4>(tokn, embedding, bufA, row, seg);   // bufA dead until next L0
      const int rclamp = l15 < 4 ? l15 : 3;                  // bufC bounds; rows>=4 discarded
      floatx4 acc[2];
      mfma_k256(bufC + rclamp * STRIDE + quad * 8, Wf, acc);
      const int mrow = quad * 4;
#pragma unroll
      for (int i = 0; i < 2; ++i) {
        const int col = (nbase + i) * 16 + l15;
#pragma unroll
        for (int r = 0; r < 4; ++r) {
          const int mr = mrow + r;                 // mr<4 valid: sample mr>>1, node mr&1
          if (mr < 4) {
            float v = fast_tanh(acc[i][r] + bias[i]);
            bufB[(mr >> 1) * STRIDE + (mr & 1) * 128 + col] = (_Float16)v;
          }
        }
      }
    }
    __syncthreads();

    // ---- batched L6 + classifier partials; + prefetch chunk 1 ----
    {
      gather_chunk<4, 8>(tokn, embedding, bufA, row, seg);
      floatx4 acc[2];
      mfma_k256(bufB + l15 * STRIDE + quad * 8, Wf, acc);    // rows 0-1 valid = roots s0,s1
      float part[2][3] = {{0.f, 0.f, 0.f}, {0.f, 0.f, 0.f}};
      if (quad == 0) {
#pragma unroll
        for (int i = 0; i < 2; ++i) {
#pragma unroll
          for (int rr = 0; rr < 2; ++rr) {         // rr = sample
            float v = fast_tanh(acc[i][rr] + bias[i]);
#pragma unroll
            for (int o = 0; o < 3; ++o) part[rr][o] = fmaf(v, wc[i][o], part[rr][o]);
          }
        }
      }
#pragma unroll
      for (int rr = 0; rr < 2; ++rr) {
#pragma unroll
        for (int o = 0; o < 3; ++o) {
          float v = part[rr][o];                   // nonzero only in quad-0 lanes
          v += __shfl_down(v, 8);
          v += __shfl_down(v, 4);
          v += __shfl_down(v, 2);
          v += __shfl_down(v, 1);
          if (lane == 0) wavepart[wid][rr][o] = v;
        }
      }
    }
    __syncthreads();
    if (tid < 6) {
      const int rr = tid / 3, o = tid - 3 * rr;
      float v = wavepart[0][rr][o] + wavepart[1][rr][o]
              + wavepart[2][rr][o] + wavepart[3][rr][o];
      out[(2 * p + rr) * 3 + o] = v + b_cls[o];
    }
    // next L0 reads bufA (prefetched leaves: writes completed before the wavepart barrier)
    // and writes bufB (L6's bufB reads also completed before that barrier) -> safe.
  }
}

extern "C" void kernel_launch(void* const* d_in, const int* in_sizes, int n_in,
                              void* d_out, int out_size, void* d_ws, size_t ws_size,
                              hipStream_t stream) {
  const int*   tokens    = (const int*)d_in[0];
  const float* embedding = (const float*)d_in[1];
  const float* W_tree    = (const float*)d_in[2];
  const float* b_tree    = (const float*)d_in[3];
  const float* W_cls     = (const float*)d_in[4];
  const float* b_cls     = (const float*)d_in[5];
  float* out = (float*)d_out;

  dim3 grid(768), block(256);   // 3 blocks/CU x 256 CUs; grid-stride over 2048 pairs
  tree_kernel<<<grid, block, 0, stream>>>(tokens, embedding, W_tree, b_tree, W_cls, b_cls, out);
}

// Round 13
// 154.304 us; speedup vs baseline: 1.5650x; 1.1905x over previous
//
#include <hip/hip_runtime.h>
#include <hip/hip_fp16.h>

// Tree NN: reps = emb[tokens] (4096 x 128 x 128); 7x: reps = tanh(concat(pairs) @ W_tree^T + b);
// out = root @ W_cls^T + b_cls.
//
// R13 = R9 (best: 85us/157us, lb(256,3)) + the two safe pieces of R12:
//  1. Conflict-free gather writes (thread t -> row t&63, seg t>>6; same pair-contig LDS
//     layout; measured -3.15M conflict cycles in R12).
//  2. Token preload one section early (1-2 VGPR): s1 token loads during s0's gather,
//     next-pair-s0 token during s1's gather -> removes the serial token->embedding
//     latency chain (~200-900 cyc) from every gather section head.
// NOT kept from R12: lb(256,2) (occupancy collapsed 30->17.4%) and tail gather-prefetch
// (barrier drains vmcnt after ~130 cyc of overlap; +19MB FETCH for nothing).
//
// Wave w owns output n-tiles {2w,2w+1} at every level (Wf[2][8] = 64 VGPR of W-fragments).
// Activations in LDS, pair-contiguous so concat(left,right) is free. Per-sample phase-1
// gather,L0..L4 (stash L4-out in bufC); batched tail L5,L6+classifier per pair.
// fp16 MFMA 16x16x32 (K-split 2 independent 4-chains), fp32 accumulate/tanh/classifier.

typedef _Float16 half8 __attribute__((ext_vector_type(8)));
typedef float floatx4 __attribute__((ext_vector_type(4)));

#define STRIDE 264   // 256 + 8 fp16 pad: A-row ds_read_b128 conflict-free
#define UROW   33    // uint4 per row
#define NPAIR  2048

__device__ __forceinline__ float fast_tanh(float x) {
  // No clamp needed: e=inf -> 1; e=0 -> -1. Inputs never NaN.
  float e = __expf(2.f * x);
  return 1.f - 2.f * __builtin_amdgcn_rcpf(e + 1.f);
}

__device__ __forceinline__ unsigned pkrtz(float a, float b) {
  auto h = __builtin_amdgcn_cvt_pkrtz(a, b);   // __fp16 ext_vector(2)
  return __builtin_bit_cast(unsigned, h);
}

// Gather: thread (row=t&63, seg=t>>6) covers leaf 2*row+(seg>>1), feature-half seg&1.
// Writes 8 uint4 at row*33 + seg*8 + j: 8 consecutive lanes hit 8 consecutive rows ->
// distinct bank-quads -> conflict-free phases. Layout identical to R9 (pair-contiguous).
__device__ __forceinline__ void gather_leafhalf(int tok, const float* __restrict__ emb,
                                                _Float16* buf, int row, int seg) {
  const float4* src = (const float4*)emb + (size_t)tok * 32 + (seg & 1) * 16;
  uint4* dst = (uint4*)buf + row * UROW + seg * 8;
#pragma unroll
  for (int j = 0; j < 8; ++j) {
    float4 x = src[2 * j], y = src[2 * j + 1];
    uint4 w;
    w.x = pkrtz(x.x, x.y); w.y = pkrtz(x.z, x.w);
    w.z = pkrtz(y.x, y.y); w.w = pkrtz(y.z, y.w);
    dst[j] = w;
  }
}

// K=256 MFMA for one 16-row m-tile, 2 n-tiles, K-split into 2 independent 4-chains.
// A-frag: A[m=lane&15][k=quad*8+j]; B-frag: B[k=quad*8+j][n=lane&15];
// D: col=lane&15, row=quad*4+reg (verified layouts, learn_hip m89/m91).
__device__ __forceinline__ void mfma_k256(const _Float16* arow, const half8 (&Wf)[2][8],
                                          floatx4 (&accO)[2]) {
  floatx4 aA[2], aB[2];
  aA[0] = (floatx4){0.f, 0.f, 0.f, 0.f}; aA[1] = (floatx4){0.f, 0.f, 0.f, 0.f};
  aB[0] = (floatx4){0.f, 0.f, 0.f, 0.f}; aB[1] = (floatx4){0.f, 0.f, 0.f, 0.f};
#pragma unroll
  for (int ks = 0; ks < 4; ++ks) {
    half8 x0 = *(const half8*)(arow + ks * 32);
    half8 x1 = *(const half8*)(arow + (ks + 4) * 32);
    aA[0] = __builtin_amdgcn_mfma_f32_16x16x32_f16(x0, Wf[0][ks],     aA[0], 0, 0, 0);
    aB[0] = __builtin_amdgcn_mfma_f32_16x16x32_f16(x1, Wf[0][ks + 4], aB[0], 0, 0, 0);
    aA[1] = __builtin_amdgcn_mfma_f32_16x16x32_f16(x0, Wf[1][ks],     aA[1], 0, 0, 0);
    aB[1] = __builtin_amdgcn_mfma_f32_16x16x32_f16(x1, Wf[1][ks + 4], aB[1], 0, 0, 0);
  }
  accO[0] = aA[0] + aB[0];
  accO[1] = aA[1] + aB[1];
}

// One wave: its 2 n-tiles for MT m-tiles; pair-contiguous store, MOUT row mask.
// Stale rows above MOUT always hold finite tanh/leaf values; masked at store.
template<int MT, int MOUT>
__device__ __forceinline__ void level_std(
    const _Float16* inb, _Float16* outb,
    const half8 (&Wf)[2][8], const float (&bias)[2],
    int nbase, int l15, int quad)
{
  floatx4 acc[MT][2];
  if (MT == 1) {
    floatx4 a2[2];
    mfma_k256(inb + l15 * STRIDE + quad * 8, Wf, a2);
    acc[0][0] = a2[0]; acc[0][1] = a2[1];
  } else {
#pragma unroll
    for (int m = 0; m < MT; ++m) {
      acc[m][0] = (floatx4){0.f, 0.f, 0.f, 0.f};
      acc[m][1] = (floatx4){0.f, 0.f, 0.f, 0.f};
    }
#pragma unroll
    for (int m = 0; m < MT; ++m) {
      const _Float16* arow = inb + (m * 16 + l15) * STRIDE + quad * 8;
#pragma unroll
      for (int ks = 0; ks < 8; ++ks) {
        half8 a = *(const half8*)(arow + ks * 32);
        acc[m][0] = __builtin_amdgcn_mfma_f32_16x16x32_f16(a, Wf[0][ks], acc[m][0], 0, 0, 0);
        acc[m][1] = __builtin_amdgcn_mfma_f32_16x16x32_f16(a, Wf[1][ks], acc[m][1], 0, 0, 0);
      }
    }
  }

  const int mrow = quad * 4;
#pragma unroll
  for (int m = 0; m < MT; ++m)
#pragma unroll
    for (int i = 0; i < 2; ++i) {
      const int col = (nbase + i) * 16 + l15;
#pragma unroll
      for (int r = 0; r < 4; ++r) {
        const int node = m * 16 + mrow + r;
        if (node < MOUT) {
          float v = fast_tanh(acc[m][i][r] + bias[i]);
          outb[(node >> 1) * STRIDE + (node & 1) * 128 + col] = (_Float16)v;
        }
      }
    }
}

__global__ __launch_bounds__(256, 3)   // proven config: cap 80 >= demand ~76, 3 blocks/CU
void tree_kernel(const int* __restrict__ tokens,
                 const float* __restrict__ embedding,
                 const float* __restrict__ W_tree,
                 const float* __restrict__ b_tree,
                 const float* __restrict__ W_cls,
                 const float* __restrict__ b_cls,
                 float* __restrict__ out)
{
  __shared__ __align__(16) _Float16 bufA[64 * STRIDE];   // leaves / even outputs (33.8 KB)
  __shared__ __align__(16) _Float16 bufB[32 * STRIDE];   // odd outputs (16.9 KB)
  __shared__ __align__(16) _Float16 bufC[4 * STRIDE];    // pair stash: L4 outs (2.1 KB)
  __shared__ float wavepart[4][2][3];                    // classifier partials (96 B)

  const int tid  = threadIdx.x;
  const int wid  = tid >> 6;
  const int lane = tid & 63;
  const int l15  = lane & 15;
  const int quad = lane >> 4;
  const int nbase = wid * 2;               // this wave's n-tile base (features [32*wid,32*wid+32))
  const int row  = tid & 63;               // gather destination row
  const int seg  = tid >> 6;               // gather leaf-half / feature-half segment
  const int tidx = 2 * row + (seg >> 1);   // this thread's token index within a sample

  // ---- stage this wave's 2 n-tiles of W_tree as B-fragments (64 VGPR) ----
  // B[k][n] = W_tree[e=n][h=k]  (einsum 'bnh,eh->bne' => out = comb @ W^T)
  half8 Wf[2][8];
#pragma unroll
  for (int i = 0; i < 2; ++i) {
    const int e = (nbase + i) * 16 + l15;
#pragma unroll
    for (int ks = 0; ks < 8; ++ks) {
      const int k = ks * 32 + quad * 8;
      const float4* p = (const float4*)(W_tree + e * 256 + k);
      float4 lo = p[0], hi = p[1];
      half8 f;
      f[0] = (_Float16)lo.x; f[1] = (_Float16)lo.y; f[2] = (_Float16)lo.z; f[3] = (_Float16)lo.w;
      f[4] = (_Float16)hi.x; f[5] = (_Float16)hi.y; f[6] = (_Float16)hi.z; f[7] = (_Float16)hi.w;
      Wf[i][ks] = f;
    }
  }
  float bias[2];
#pragma unroll
  for (int i = 0; i < 2; ++i) bias[i] = b_tree[(nbase + i) * 16 + l15];

  // classifier weights for this lane's 2 columns: loop-invariant (6 VGPR)
  float wc[2][3];
#pragma unroll
  for (int i = 0; i < 2; ++i) {
    const int col = (nbase + i) * 16 + l15;
#pragma unroll
    for (int o = 0; o < 3; ++o) wc[i][o] = W_cls[o * 128 + col];
  }

  int tokA = tokens[(2 * blockIdx.x) * 128 + tidx];   // preloaded s0 token (first pair)

#pragma unroll 1
  for (int p = blockIdx.x; p < NPAIR; p += gridDim.x) {
    int pn = p + gridDim.x;
    if (pn >= NPAIR) pn = p;               // last iteration: harmless self-reload

    // ---- s0 gather (token preloaded) + preload s1 token ----
    gather_leafhalf(tokA, embedding, bufA, row, seg);
    const int tokB = tokens[(2 * p + 1) * 128 + tidx];
    __syncthreads();

    // ---- s0 levels: L0..L4, stash L4-out in bufC rows 0-1 ----
    level_std<4, 64>(bufA, bufB, Wf, bias, nbase, l15, quad);   // L0
    __syncthreads();
    level_std<2, 32>(bufB, bufA, Wf, bias, nbase, l15, quad);   // L1
    __syncthreads();
    level_std<1, 16>(bufA, bufB, Wf, bias, nbase, l15, quad);   // L2
    __syncthreads();
    level_std<1,  8>(bufB, bufA, Wf, bias, nbase, l15, quad);   // L3
    __syncthreads();
    level_std<1,  4>(bufA, bufC, Wf, bias, nbase, l15, quad);   // L4 -> bufC rows 0-1
    __syncthreads();

    // ---- s1 gather (token preloaded) + preload next-pair s0 token ----
    gather_leafhalf(tokB, embedding, bufA, row, seg);
    tokA = tokens[(2 * pn) * 128 + tidx];
    __syncthreads();

    // ---- s1 levels: L0..L4, stash L4-out in bufC rows 2-3 ----
    level_std<4, 64>(bufA, bufB, Wf, bias, nbase, l15, quad);   // L0
    __syncthreads();
    level_std<2, 32>(bufB, bufA, Wf, bias, nbase, l15, quad);   // L1
    __syncthreads();
    level_std<1, 16>(bufA, bufB, Wf, bias, nbase, l15, quad);   // L2
    __syncthreads();
    level_std<1,  8>(bufB, bufA, Wf, bias, nbase, l15, quad);   // L3
    __syncthreads();
    level_std<1,  4>(bufA, bufC + 2 * STRIDE, Wf, bias, nbase, l15, quad); // L4 -> rows 2-3
    __syncthreads();

    // ---- batched L5: bufC rows 0-3 -> bufA rows 0-1 ----
    {
      const int rclamp = l15 < 4 ? l15 : 3;          // bufC bounds; rows>=4 discarded
      floatx4 acc[2];
      mfma_k256(bufC + rclamp * STRIDE + quad * 8, Wf, acc);
      const int mrow = quad * 4;
#pragma unroll
      for (int i = 0; i < 2; ++i) {
        const int col = (nbase + i) * 16 + l15;
#pragma unroll
        for (int r = 0; r < 4; ++r) {
          const int mr = mrow + r;                   // mr<4 valid: sample mr>>1, node mr&1
          if (mr < 4) {
            float v = fast_tanh(acc[i][r] + bias[i]);
            bufA[(mr >> 1) * STRIDE + (mr & 1) * 128 + col] = (_Float16)v;
          }
        }
      }
    }
    __syncthreads();

    // ---- batched L6 + classifier partials from registers ----
    {
      floatx4 acc[2];
      mfma_k256(bufA + l15 * STRIDE + quad * 8, Wf, acc);  // rows 0-1 valid = roots s0,s1
      float part[2][3] = {{0.f, 0.f, 0.f}, {0.f, 0.f, 0.f}};
      if (quad == 0) {
#pragma unroll
        for (int i = 0; i < 2; ++i) {
#pragma unroll
          for (int rr = 0; rr < 2; ++rr) {           // rr = sample
            float v = fast_tanh(acc[i][rr] + bias[i]);
#pragma unroll
            for (int o = 0; o < 3; ++o) part[rr][o] = fmaf(v, wc[i][o], part[rr][o]);
          }
        }
      }
#pragma unroll
      for (int rr = 0; rr < 2; ++rr) {
#pragma unroll
        for (int o = 0; o < 3; ++o) {
          float v = part[rr][o];                     // nonzero only in quad-0 lanes
          v += __shfl_down(v, 8);
          v += __shfl_down(v, 4);
          v += __shfl_down(v, 2);
          v += __shfl_down(v, 1);
          if (lane == 0) wavepart[wid][rr][o] = v;
        }
      }
    }
    __syncthreads();
    if (tid < 6) {
      const int rr = tid / 3, o = tid - 3 * rr;
      float v = wavepart[0][rr][o] + wavepart[1][rr][o]
              + wavepart[2][rr][o] + wavepart[3][rr][o];
      out[(2 * p + rr) * 3 + o] = v + b_cls[o];
    }
    // next pair's gather overwrites bufA: all L6 bufA reads completed before the wavepart
    // barrier; wavepart next written 13 barriers later -> safe.
  }
}

extern "C" void kernel_launch(void* const* d_in, const int* in_sizes, int n_in,
                              void* d_out, int out_size, void* d_ws, size_t ws_size,
                              hipStream_t stream) {
  const int*   tokens    = (const int*)d_in[0];
  const float* embedding = (const float*)d_in[1];
  const float* W_tree    = (const float*)d_in[2];
  const float* b_tree    = (const float*)d_in[3];
  const float* W_cls     = (const float*)d_in[4];
  const float* b_cls     = (const float*)d_in[5];
  float* out = (float*)d_out;

  dim3 grid(768), block(256);   // 3 blocks/CU x 256 CUs; grid-stride over 2048 pairs
  tree_kernel<<<grid, block, 0, stream>>>(tokens, embedding, W_tree, b_tree, W_cls, b_cls, out);
}